// Round 6
// baseline (972.788 us; speedup 1.0000x reference)
//
#include <hip/hip_runtime.h>

#define NN 100000
#define NE 1600000
#define SORT_M 131072  // next pow2 >= NN
#define NB_SCAN 98     // ceil(NN/1024)
#define TS 8192        // bitonic local tile (64KB LDS)

// ---------------- CSR build ----------------
__global__ void zero_counts(int* c) {
    int i = blockIdx.x * blockDim.x + threadIdx.x;
    if (i < NN) c[i] = 0;
}

__global__ void count_dst(const int* __restrict__ dst, int* c) {
    int e = blockIdx.x * blockDim.x + threadIdx.x;
    if (e < NE) atomicAdd(&c[dst[e]], 1);
}

// 3-phase exclusive scan of counts[NN] -> offs/cursor; p3 also emits dinv
__global__ void scan_p1(const int* __restrict__ c, int* __restrict__ bsums) {
    __shared__ int red[256];
    int b = blockIdx.x, t = threadIdx.x;
    int s = 0;
    for (int i = t; i < 1024; i += 256) {
        int idx = b * 1024 + i;
        s += (idx < NN) ? c[idx] : 0;
    }
    red[t] = s; __syncthreads();
    for (int o = 128; o; o >>= 1) {
        if (t < o) red[t] += red[t + o];
        __syncthreads();
    }
    if (t == 0) bsums[b] = red[0];
}

__global__ void scan_p2(int* bsums) {  // single block of 128, NB_SCAN<=128
    __shared__ int tmp[128];
    int t = threadIdx.x;
    int v = (t < NB_SCAN) ? bsums[t] : 0;
    tmp[t] = v; __syncthreads();
    for (int o = 1; o < 128; o <<= 1) {
        int add = (t >= o) ? tmp[t - o] : 0;
        __syncthreads();
        tmp[t] += add;
        __syncthreads();
    }
    if (t < NB_SCAN) bsums[t] = tmp[t] - v;  // exclusive
}

__global__ void scan_p3(const int* __restrict__ c, const int* __restrict__ bsums,
                        int* __restrict__ offs, int* __restrict__ cursor,
                        float* __restrict__ dinv) {
    __shared__ int thr[256];
    int b = blockIdx.x, t = threadIdx.x;
    int base = b * 1024 + t * 4;
    int cv[4];
#pragma unroll
    for (int j = 0; j < 4; j++) cv[j] = (base + j < NN) ? c[base + j] : 0;
    int s = cv[0] + cv[1] + cv[2] + cv[3];
    thr[t] = s; __syncthreads();
    for (int o = 1; o < 256; o <<= 1) {
        int add = (t >= o) ? thr[t - o] : 0;
        __syncthreads();
        thr[t] += add;
        __syncthreads();
    }
    int ex = thr[t] - s + bsums[b];
#pragma unroll
    for (int j = 0; j < 4; j++) {
        if (base + j < NN) {
            offs[base + j] = ex;
            cursor[base + j] = ex;
            dinv[base + j] = rsqrtf((float)(cv[j] + 1));  // +1 self-loop
            ex += cv[j];
        }
    }
}

// pass-filtered scatter: only edges with dst in [pass*32768, (pass+1)*32768)
// -> writes cluster into a ~2MB contiguous CSR window that L2 can combine.
// CSR entry = src only (norm folded into GEMM via dinv pre-scaling).
__global__ void csr_scatter_p(const int* __restrict__ src, const int* __restrict__ dst,
                              int* cursor, int* __restrict__ csr, int pass) {
    int e = blockIdx.x * blockDim.x + threadIdx.x;
    if (e >= NE) return;
    int d = dst[e];
    if ((d >> 15) != pass) return;
    int p = atomicAdd(&cursor[d], 1);
    csr[p] = src[e];
}

// ---------------- weight swizzles (single kernel) ----------------
__device__ inline void swz_w(const float* __restrict__ W, float4* __restrict__ o, int idx) {
    int k4 = idx >> 6, co = idx & 63;
    o[idx] = make_float4(W[(4 * k4 + 0) * 64 + co], W[(4 * k4 + 1) * 64 + co],
                         W[(4 * k4 + 2) * 64 + co], W[(4 * k4 + 3) * 64 + co]);
}

__device__ inline void swz_c(const float* __restrict__ w, float4* __restrict__ o, int idx) {
    int co = idx & 63, j = (idx >> 6) & 15, k = idx >> 10;
    int b = co * 320 + k;  // w[co][ci][k] = w[co*320 + ci*5 + k], ci=4j+t
    o[idx] = make_float4(w[b + (4 * j + 0) * 5], w[b + (4 * j + 1) * 5],
                         w[b + (4 * j + 2) * 5], w[b + (4 * j + 3) * 5]);
}

__global__ void swizzle_all(const float* W0, const float* W1, const float* W2,
                            const float* lw, const float* c1w, const float* c2w,
                            float4* w0sw, float4* w1sw, float4* w2sw,
                            float4* linsw, float4* c1sw, float4* c2sw) {
    int idx = blockIdx.x * blockDim.x + threadIdx.x;
    if (idx < 2048)        swz_w(W0, w0sw, idx);
    else if (idx < 3072)   swz_w(W1, w1sw, idx - 2048);
    else if (idx < 4096)   swz_w(W2, w2sw, idx - 3072);
    else if (idx < 6144)   swz_w(lw, linsw, idx - 4096);
    else if (idx < 11264)  swz_c(c1w, c1sw, idx - 6144);
    else if (idx < 16384)  swz_c(c2w, c2sw, idx - 11264);
}

// ---------------- GEMM: Y[N][64] = (relu?)X[N][K] @ W[K][64] * dinv[row] ----------------
// 64 rows/block, 2 cols/thread; epilogue scales row by dinv (norm-free CSR scheme)
template <int K, bool RELU>
__global__ __launch_bounds__(256) void gemm64r(const float* __restrict__ X,
                                               const float4* __restrict__ Wsw,
                                               const float* __restrict__ dinv,
                                               float* __restrict__ Y, int n) {
    constexpr int KV = K / 4;
    constexpr int SH = (KV == 32) ? 5 : 4;
    __shared__ float4 xs[64][KV];
    int tid = threadIdx.x;
    int r0 = blockIdx.x * 64;
    for (int idx = tid; idx < 64 * KV; idx += 256) {
        int r = idx >> SH, k4 = idx & (KV - 1);
        int row = r0 + r;
        float4 v = make_float4(0.f, 0.f, 0.f, 0.f);
        if (row < n) v = *reinterpret_cast<const float4*>(X + (size_t)row * K + 4 * k4);
        if (RELU) {
            v.x = fmaxf(v.x, 0.f); v.y = fmaxf(v.y, 0.f);
            v.z = fmaxf(v.z, 0.f); v.w = fmaxf(v.w, 0.f);
        }
        xs[r][k4] = v;
    }
    __syncthreads();
    int co2 = tid & 31, rg = tid >> 5;  // rg 0..7, 8 rows each
    int c0 = 2 * co2;
    float acc0[8], acc1[8];
#pragma unroll
    for (int i = 0; i < 8; i++) { acc0[i] = 0.f; acc1[i] = 0.f; }
    for (int k4 = 0; k4 < KV; k4++) {
        float4 wa = Wsw[k4 * 64 + c0];
        float4 wb = Wsw[k4 * 64 + c0 + 1];
#pragma unroll
        for (int i = 0; i < 8; i++) {
            float4 xv = xs[rg * 8 + i][k4];
            acc0[i] += xv.x * wa.x + xv.y * wa.y + xv.z * wa.z + xv.w * wa.w;
            acc1[i] += xv.x * wb.x + xv.y * wb.y + xv.z * wb.z + xv.w * wb.w;
        }
    }
#pragma unroll
    for (int i = 0; i < 8; i++) {
        int row = r0 + rg * 8 + i;
        if (row < n) {
            float dv = dinv[row];
            *reinterpret_cast<float2*>(Y + (size_t)row * 64 + c0) =
                make_float2(acc0[i] * dv, acc1[i] * dv);
        }
    }
}

// ---------------- pull aggregation: one wave per node ----------------
// H is pre-scaled by dinv (H' = H*dinv): out[d] = dv*(H'[d] + sum H'[src]) + bias
// SCORE: fuse score projection AND sort-key/val emission (lane 0)
template <int SCORE>
__global__ __launch_bounds__(256) void agg_pull(const float* __restrict__ H,
                                                const int* __restrict__ offs,
                                                const int* __restrict__ counts,
                                                const int* __restrict__ csr,
                                                const float* __restrict__ dinv,
                                                const float* __restrict__ bias,
                                                float* __restrict__ Y,
                                                const float* __restrict__ Wp,
                                                const float* __restrict__ bp,
                                                float* __restrict__ sc,
                                                unsigned* __restrict__ keys,
                                                int* __restrict__ vals) {
    int lane = threadIdx.x & 63;
    int node = blockIdx.x * 4 + (threadIdx.x >> 6);
    if (node >= NN) return;
    float dv = dinv[node];
    float acc = H[(size_t)node * 64 + lane];  // self-loop (pre-scaled)
    int off = offs[node], cnt = counts[node];
    int i = 0;
    for (; i + 7 < cnt; i += 8) {
        int p0 = csr[off + i];
        int p1 = csr[off + i + 1];
        int p2 = csr[off + i + 2];
        int p3 = csr[off + i + 3];
        int p4 = csr[off + i + 4];
        int p5 = csr[off + i + 5];
        int p6 = csr[off + i + 6];
        int p7 = csr[off + i + 7];
        float h0 = H[(size_t)p0 * 64 + lane];
        float h1 = H[(size_t)p1 * 64 + lane];
        float h2 = H[(size_t)p2 * 64 + lane];
        float h3 = H[(size_t)p3 * 64 + lane];
        float h4 = H[(size_t)p4 * 64 + lane];
        float h5 = H[(size_t)p5 * 64 + lane];
        float h6 = H[(size_t)p6 * 64 + lane];
        float h7 = H[(size_t)p7 * 64 + lane];
        acc += ((h0 + h1) + (h2 + h3)) + ((h4 + h5) + (h6 + h7));
    }
    for (; i < cnt; i++) {
        acc += H[(size_t)csr[off + i] * 64 + lane];
    }
    float o = acc * dv + bias[lane];
    Y[(size_t)node * 64 + lane] = o;
    if (SCORE) {
        float v = o * Wp[lane];
        for (int of = 32; of; of >>= 1) v += __shfl_down(v, of, 64);
        if (lane == 0) {
            float s = v + bp[0];
            sc[node] = s;
            unsigned u = __float_as_uint(s);
            u = (u & 0x80000000u) ? ~u : (u | 0x80000000u);
            keys[node] = u;
            vals[node] = node;
        }
    }
}

// ---------------- bitonic sort (pad fused into local-sort load) ----------------
__global__ __launch_bounds__(1024) void bitonic_local_sort8k(unsigned* key, int* val) {
    __shared__ unsigned sk[TS];
    __shared__ int sv[TS];
    int t = threadIdx.x;
    int base = blockIdx.x * TS;
    for (int i = t; i < TS; i += 1024) {
        if (base + i < NN) { sk[i] = key[base + i]; sv[i] = val[base + i]; }
        else               { sk[i] = 0xFFFFFFFFu;  sv[i] = 0x7FFFFFFF; }
    }
    for (int k = 2; k <= TS; k <<= 1) {
        for (int j = k >> 1; j > 0; j >>= 1) {
            __syncthreads();
            for (int c = t; c < TS / 2; c += 1024) {
                int i = 2 * c - (c & (j - 1));
                bool up = (((base + i) & k) == 0);
                unsigned a = sk[i], b = sk[i + j];
                if ((a > b) == up) {
                    sk[i] = b; sk[i + j] = a;
                    int tv = sv[i]; sv[i] = sv[i + j]; sv[i + j] = tv;
                }
            }
        }
    }
    __syncthreads();
    for (int i = t; i < TS; i += 1024) { key[base + i] = sk[i]; val[base + i] = sv[i]; }
}

__global__ void bitonic_global(unsigned* key, int* val, int j, int k) {
    int i = blockIdx.x * blockDim.x + threadIdx.x;
    int ixj = i ^ j;
    if (ixj > i) {
        bool up = ((i & k) == 0);
        unsigned a = key[i], b = key[ixj];
        if ((a > b) == up) {
            key[i] = b; key[ixj] = a;
            int tv = val[i]; val[i] = val[ixj]; val[ixj] = tv;
        }
    }
}

__global__ __launch_bounds__(1024) void bitonic_local_merge8k(unsigned* key, int* val, int k) {
    __shared__ unsigned sk[TS];
    __shared__ int sv[TS];
    int t = threadIdx.x;
    int base = blockIdx.x * TS;
    for (int i = t; i < TS; i += 1024) { sk[i] = key[base + i]; sv[i] = val[base + i]; }
    for (int j = TS / 2; j > 0; j >>= 1) {
        __syncthreads();
        for (int c = t; c < TS / 2; c += 1024) {
            int i = 2 * c - (c & (j - 1));
            bool up = (((base + i) & k) == 0);
            unsigned a = sk[i], b = sk[i + j];
            if ((a > b) == up) {
                sk[i] = b; sk[i + j] = a;
                int tv = sv[i]; sv[i] = sv[i + j]; sv[i + j] = tv;
            }
        }
    }
    __syncthreads();
    for (int i = t; i < TS; i += 1024) { key[base + i] = sk[i]; val[base + i] = sv[i]; }
}

// ---------------- conv1d (C=64, K=5, pad=2), 64 rows/block, 2 cols/thread ----------------
// GATHER: stage score[v]*X[v] for v=vals[row] (fuses build_sorted) + emit inverse perm
template <bool GATHER>
__global__ __launch_bounds__(256) void conv1d_k(const float* __restrict__ X,
                                                const int* __restrict__ vals,
                                                const float* __restrict__ sc,
                                                const float4* __restrict__ cw,
                                                const float* __restrict__ bias,
                                                float* __restrict__ Y, int relu,
                                                int* __restrict__ inv) {
    __shared__ float4 xs[68][16];
    int tid = threadIdx.x;
    int r0 = blockIdx.x * 64;
    for (int idx = tid; idx < 68 * 16; idx += 256) {
        int r = idx >> 4, k4 = idx & 15;
        int row = r0 + r - 2;
        float4 v = make_float4(0.f, 0.f, 0.f, 0.f);
        if (row >= 0 && row < NN) {
            if (GATHER) {
                int vs = vals[row];
                float s = sc[vs];
                v = *reinterpret_cast<const float4*>(X + (size_t)vs * 64 + 4 * k4);
                v.x *= s; v.y *= s; v.z *= s; v.w *= s;
                if (k4 == 0) inv[vs] = row;  // fused inverse perm (halo dups benign)
            } else {
                v = *reinterpret_cast<const float4*>(X + (size_t)row * 64 + 4 * k4);
            }
        }
        xs[r][k4] = v;
    }
    __syncthreads();
    int co2 = tid & 31, rg = tid >> 5;  // rg 0..7, 8 rows each
    int c0 = 2 * co2;
    float acc0[8], acc1[8];
#pragma unroll
    for (int i = 0; i < 8; i++) { acc0[i] = 0.f; acc1[i] = 0.f; }
    for (int j = 0; j < 16; j++) {
        float4 xv[12];
#pragma unroll
        for (int t2 = 0; t2 < 12; t2++) xv[t2] = xs[rg * 8 + t2][j];
#pragma unroll
        for (int k = 0; k < 5; k++) {
            float4 wa = cw[(k * 16 + j) * 64 + c0];
            float4 wb = cw[(k * 16 + j) * 64 + c0 + 1];
#pragma unroll
            for (int i = 0; i < 8; i++) {
                float4 x4 = xv[i + k];
                acc0[i] += x4.x * wa.x + x4.y * wa.y + x4.z * wa.z + x4.w * wa.w;
                acc1[i] += x4.x * wb.x + x4.y * wb.y + x4.z * wb.z + x4.w * wb.w;
            }
        }
    }
    float b0v = bias[c0], b1v = bias[c0 + 1];
#pragma unroll
    for (int i = 0; i < 8; i++) {
        int row = r0 + rg * 8 + i;
        if (row < NN) {
            float o0 = acc0[i] + b0v, o1 = acc1[i] + b1v;
            if (relu) { o0 = fmaxf(o0, 0.f); o1 = fmaxf(o1, 0.f); }
            *reinterpret_cast<float2*>(Y + (size_t)row * 64 + c0) = make_float2(o0, o1);
        }
    }
}

// ---------------- final: out[n] = [C[n], H2[inv[n]]] @ lin_w + lb, 64 rows/block ----------------
__global__ __launch_bounds__(256) void final_k(const float* __restrict__ C,
                                               const float* __restrict__ H2,
                                               const int* __restrict__ inv,
                                               const float4* __restrict__ linsw,
                                               const float* __restrict__ lb,
                                               float* __restrict__ Yout) {
    __shared__ float4 xs[64][32];
    int tid = threadIdx.x;
    int r0 = blockIdx.x * 64;
    for (int idx = tid; idx < 64 * 32; idx += 256) {
        int r = idx >> 5, k4 = idx & 31;
        int row = r0 + r;
        float4 v = make_float4(0.f, 0.f, 0.f, 0.f);
        if (row < NN) {
            if (k4 < 16) v = *reinterpret_cast<const float4*>(C + (size_t)row * 64 + 4 * k4);
            else v = *reinterpret_cast<const float4*>(H2 + (size_t)inv[row] * 64 + 4 * (k4 - 16));
        }
        xs[r][k4] = v;
    }
    __syncthreads();
    int co2 = tid & 31, rg = tid >> 5;
    int c0 = 2 * co2;
    float acc0[8], acc1[8];
#pragma unroll
    for (int i = 0; i < 8; i++) { acc0[i] = 0.f; acc1[i] = 0.f; }
    for (int k4 = 0; k4 < 32; k4++) {
        float4 wa = linsw[k4 * 64 + c0];
        float4 wb = linsw[k4 * 64 + c0 + 1];
#pragma unroll
        for (int i = 0; i < 8; i++) {
            float4 xv = xs[rg * 8 + i][k4];
            acc0[i] += xv.x * wa.x + xv.y * wa.y + xv.z * wa.z + xv.w * wa.w;
            acc1[i] += xv.x * wb.x + xv.y * wb.y + xv.z * wb.z + xv.w * wb.w;
        }
    }
    float b0v = lb[c0], b1v = lb[c0 + 1];
#pragma unroll
    for (int i = 0; i < 8; i++) {
        int row = r0 + rg * 8 + i;
        if (row < NN)
            *reinterpret_cast<float2*>(Yout + (size_t)row * 64 + c0) =
                make_float2(acc0[i] + b0v, acc1[i] + b1v);
    }
}

extern "C" void kernel_launch(void* const* d_in, const int* in_sizes, int n_in,
                              void* d_out, int out_size, void* d_ws, size_t ws_size,
                              hipStream_t stream) {
    const float* x   = (const float*)d_in[0];
    const int*   ei  = (const int*)d_in[1];
    const float* W0  = (const float*)d_in[2];
    const float* b0  = (const float*)d_in[3];
    const float* W1  = (const float*)d_in[4];
    const float* b1  = (const float*)d_in[5];
    const float* W2  = (const float*)d_in[6];
    const float* b2  = (const float*)d_in[7];
    const float* Wp  = (const float*)d_in[8];
    const float* bp  = (const float*)d_in[9];
    const float* c1w = (const float*)d_in[10];
    const float* c1b = (const float*)d_in[11];
    const float* c2w = (const float*)d_in[12];
    const float* c2b = (const float*)d_in[13];
    const float* lw  = (const float*)d_in[14];
    const float* lb  = (const float*)d_in[15];
    const int* src = ei;
    const int* dst = ei + NE;

    // workspace layout
    float* A     = (float*)d_ws;                 // [NN*64]
    float* B     = A + (size_t)NN * 64;          // [NN*64]
    float* dinv  = B + (size_t)NN * 64;          // [NN]
    float* score = dinv + NN;                    // [NN]
    unsigned* keys = (unsigned*)(score + NN);    // [SORT_M]
    int* vals    = (int*)(keys + SORT_M);        // [SORT_M]
    int* inv     = vals + SORT_M;                // [NN]
    int* counts  = inv + NN;                     // [NN]
    int* offs    = counts + NN;                  // [NN]
    int* cursor  = offs + NN;                    // [NN]
    int* bsums   = cursor + NN;                  // [128]
    int* csr     = bsums + 128;                  // [NE] (src only, 4B)
    float4* w0sw  = (float4*)(csr + NE);         // 2048
    float4* w1sw  = w0sw + 2048;                 // 1024
    float4* w2sw  = w1sw + 1024;                 // 1024
    float4* linsw = w2sw + 1024;                 // 2048
    float4* c1sw  = linsw + 2048;                // 5120
    float4* c2sw  = c1sw + 5120;                 // 5120
    float* Cb = (float*)d_out;  // h1 lives in d_out; final_k overwrites block-local rows

    const int GR64 = (NN + 63) / 64;       // 1563
    const int GN4 = (NN + 3) / 4;          // 25000 (agg_pull: 4 waves/block)
    const int GE = (NE + 255) / 256;       // 6250

    // CSR build (reused by all 3 layers) + dinv
    zero_counts<<<(NN + 255) / 256, 256, 0, stream>>>(counts);
    count_dst<<<GE, 256, 0, stream>>>(dst, counts);
    scan_p1<<<NB_SCAN, 256, 0, stream>>>(counts, bsums);
    scan_p2<<<1, 128, 0, stream>>>(bsums);
    scan_p3<<<NB_SCAN, 256, 0, stream>>>(counts, bsums, offs, cursor, dinv);
    // 4 dst-range passes for write clustering (each CSR window ~2MB, L2-combinable)
    for (int pass = 0; pass < 4; pass++)
        csr_scatter_p<<<GE, 256, 0, stream>>>(src, dst, cursor, csr, pass);

    // weight swizzles (single kernel)
    swizzle_all<<<64, 256, 0, stream>>>(W0, W1, W2, lw, c1w, c2w,
                                        w0sw, w1sw, w2sw, linsw, c1sw, c2sw);

    // layer 0: A = (x@W0)*dinv ; B = dv*(selfA + sum A[src]) + b0
    gemm64r<128, false><<<GR64, 256, 0, stream>>>(x, w0sw, dinv, A, NN);
    agg_pull<0><<<GN4, 256, 0, stream>>>(A, offs, counts, csr, dinv, b0, B,
                                         nullptr, nullptr, nullptr, nullptr, nullptr);
    // layer 1
    gemm64r<64, true><<<GR64, 256, 0, stream>>>(B, w1sw, dinv, A, NN);
    agg_pull<0><<<GN4, 256, 0, stream>>>(A, offs, counts, csr, dinv, b1, B,
                                         nullptr, nullptr, nullptr, nullptr, nullptr);
    // layer 2: Cb = h1 ; score + sort keys fused
    gemm64r<64, true><<<GR64, 256, 0, stream>>>(B, w2sw, dinv, A, NN);
    agg_pull<1><<<GN4, 256, 0, stream>>>(A, offs, counts, csr, dinv, b2, Cb,
                                         Wp, bp, score, keys, vals);

    // sort (8192-elem local tiles; tail-pad fused into local sort load)
    bitonic_local_sort8k<<<SORT_M / TS, 1024, 0, stream>>>(keys, vals);
    for (int k = 2 * TS; k <= SORT_M; k <<= 1) {
        for (int j = k >> 1; j >= TS; j >>= 1)
            bitonic_global<<<SORT_M / 256, 256, 0, stream>>>(keys, vals, j, k);
        bitonic_local_merge8k<<<SORT_M / TS, 1024, 0, stream>>>(keys, vals, k);
    }

    // conv1 (gather-fused: stages score[v]*h1[v], emits inv) -> B ; conv2 -> A
    conv1d_k<true><<<GR64, 256, 0, stream>>>(Cb, vals, score, c1sw, c1b, B, 1, inv);
    conv1d_k<false><<<GR64, 256, 0, stream>>>(B, nullptr, nullptr, c2sw, c2b, A, 0, nullptr);

    // final linear
    final_k<<<GR64, 256, 0, stream>>>(Cb, A, inv, linsw, lb, (float*)d_out);
}

// Round 7
// 924.031 us; speedup vs baseline: 1.0528x; 1.0528x over previous
//
#include <hip/hip_runtime.h>

#define NN 100000
#define NE 1600000
#define NB_SCAN 98     // ceil(NN/1024)
#define RBLK 98        // radix: ceil(NN/1024)
#define NENT (256 * RBLK)
#define RSEG 25        // ceil(NENT/1024)

// ---------------- CSR build ----------------
__global__ void zero_counts(int* c) {
    int i = blockIdx.x * blockDim.x + threadIdx.x;
    if (i < NN) c[i] = 0;
}

__global__ void count_dst(const int* __restrict__ dst, int* c) {
    int e = blockIdx.x * blockDim.x + threadIdx.x;
    if (e < NE) atomicAdd(&c[dst[e]], 1);
}

// 3-phase exclusive scan of counts[NN] -> offs/cursor; p3 also emits dinv
__global__ void scan_p1(const int* __restrict__ c, int* __restrict__ bsums) {
    __shared__ int red[256];
    int b = blockIdx.x, t = threadIdx.x;
    int s = 0;
    for (int i = t; i < 1024; i += 256) {
        int idx = b * 1024 + i;
        s += (idx < NN) ? c[idx] : 0;
    }
    red[t] = s; __syncthreads();
    for (int o = 128; o; o >>= 1) {
        if (t < o) red[t] += red[t + o];
        __syncthreads();
    }
    if (t == 0) bsums[b] = red[0];
}

__global__ void scan_p2(int* bsums) {  // single block of 128, NB_SCAN<=128
    __shared__ int tmp[128];
    int t = threadIdx.x;
    int v = (t < NB_SCAN) ? bsums[t] : 0;
    tmp[t] = v; __syncthreads();
    for (int o = 1; o < 128; o <<= 1) {
        int add = (t >= o) ? tmp[t - o] : 0;
        __syncthreads();
        tmp[t] += add;
        __syncthreads();
    }
    if (t < NB_SCAN) bsums[t] = tmp[t] - v;  // exclusive
}

__global__ void scan_p3(const int* __restrict__ c, const int* __restrict__ bsums,
                        int* __restrict__ offs, int* __restrict__ cursor,
                        float* __restrict__ dinv) {
    __shared__ int thr[256];
    int b = blockIdx.x, t = threadIdx.x;
    int base = b * 1024 + t * 4;
    int cv[4];
#pragma unroll
    for (int j = 0; j < 4; j++) cv[j] = (base + j < NN) ? c[base + j] : 0;
    int s = cv[0] + cv[1] + cv[2] + cv[3];
    thr[t] = s; __syncthreads();
    for (int o = 1; o < 256; o <<= 1) {
        int add = (t >= o) ? thr[t - o] : 0;
        __syncthreads();
        thr[t] += add;
        __syncthreads();
    }
    int ex = thr[t] - s + bsums[b];
#pragma unroll
    for (int j = 0; j < 4; j++) {
        if (base + j < NN) {
            offs[base + j] = ex;
            cursor[base + j] = ex;
            dinv[base + j] = rsqrtf((float)(cv[j] + 1));  // +1 self-loop
            ex += cv[j];
        }
    }
}

// single-pass scatter (4B src-only entries; norm folded into GEMM dinv pre-scale)
__global__ void csr_scatter(const int* __restrict__ src, const int* __restrict__ dst,
                            int* cursor, int* __restrict__ csr) {
    int e = blockIdx.x * blockDim.x + threadIdx.x;
    if (e >= NE) return;
    int p = atomicAdd(&cursor[dst[e]], 1);
    csr[p] = src[e];
}

// ---------------- weight swizzles (single kernel) ----------------
__device__ inline void swz_w(const float* __restrict__ W, float4* __restrict__ o, int idx) {
    int k4 = idx >> 6, co = idx & 63;
    o[idx] = make_float4(W[(4 * k4 + 0) * 64 + co], W[(4 * k4 + 1) * 64 + co],
                         W[(4 * k4 + 2) * 64 + co], W[(4 * k4 + 3) * 64 + co]);
}

__device__ inline void swz_c(const float* __restrict__ w, float4* __restrict__ o, int idx) {
    int co = idx & 63, j = (idx >> 6) & 15, k = idx >> 10;
    int b = co * 320 + k;  // w[co][ci][k] = w[co*320 + ci*5 + k], ci=4j+t
    o[idx] = make_float4(w[b + (4 * j + 0) * 5], w[b + (4 * j + 1) * 5],
                         w[b + (4 * j + 2) * 5], w[b + (4 * j + 3) * 5]);
}

__global__ void swizzle_all(const float* W0, const float* W1, const float* W2,
                            const float* lw, const float* c1w, const float* c2w,
                            float4* w0sw, float4* w1sw, float4* w2sw,
                            float4* linsw, float4* c1sw, float4* c2sw) {
    int idx = blockIdx.x * blockDim.x + threadIdx.x;
    if (idx < 2048)        swz_w(W0, w0sw, idx);
    else if (idx < 3072)   swz_w(W1, w1sw, idx - 2048);
    else if (idx < 4096)   swz_w(W2, w2sw, idx - 3072);
    else if (idx < 6144)   swz_w(lw, linsw, idx - 4096);
    else if (idx < 11264)  swz_c(c1w, c1sw, idx - 6144);
    else if (idx < 16384)  swz_c(c2w, c2sw, idx - 11264);
}

// ---------------- GEMM: Y[N][64] = (relu?)X[N][K] @ W[K][64] * dinv[row] ----------------
template <int K, bool RELU>
__global__ __launch_bounds__(256) void gemm64r(const float* __restrict__ X,
                                               const float4* __restrict__ Wsw,
                                               const float* __restrict__ dinv,
                                               float* __restrict__ Y, int n) {
    constexpr int KV = K / 4;
    constexpr int SH = (KV == 32) ? 5 : 4;
    __shared__ float4 xs[64][KV];
    int tid = threadIdx.x;
    int r0 = blockIdx.x * 64;
    for (int idx = tid; idx < 64 * KV; idx += 256) {
        int r = idx >> SH, k4 = idx & (KV - 1);
        int row = r0 + r;
        float4 v = make_float4(0.f, 0.f, 0.f, 0.f);
        if (row < n) v = *reinterpret_cast<const float4*>(X + (size_t)row * K + 4 * k4);
        if (RELU) {
            v.x = fmaxf(v.x, 0.f); v.y = fmaxf(v.y, 0.f);
            v.z = fmaxf(v.z, 0.f); v.w = fmaxf(v.w, 0.f);
        }
        xs[r][k4] = v;
    }
    __syncthreads();
    int co2 = tid & 31, rg = tid >> 5;  // rg 0..7, 8 rows each
    int c0 = 2 * co2;
    float acc0[8], acc1[8];
#pragma unroll
    for (int i = 0; i < 8; i++) { acc0[i] = 0.f; acc1[i] = 0.f; }
    for (int k4 = 0; k4 < KV; k4++) {
        float4 wa = Wsw[k4 * 64 + c0];
        float4 wb = Wsw[k4 * 64 + c0 + 1];
#pragma unroll
        for (int i = 0; i < 8; i++) {
            float4 xv = xs[rg * 8 + i][k4];
            acc0[i] += xv.x * wa.x + xv.y * wa.y + xv.z * wa.z + xv.w * wa.w;
            acc1[i] += xv.x * wb.x + xv.y * wb.y + xv.z * wb.z + xv.w * wb.w;
        }
    }
#pragma unroll
    for (int i = 0; i < 8; i++) {
        int row = r0 + rg * 8 + i;
        if (row < n) {
            float dv = dinv[row];
            *reinterpret_cast<float2*>(Y + (size_t)row * 64 + c0) =
                make_float2(acc0[i] * dv, acc1[i] * dv);
        }
    }
}

// ---------------- pull aggregation: one wave per node ----------------
// H is pre-scaled by dinv: out[d] = dv*(H'[d] + sum H'[src]) + bias
// SCORE: fuse score projection AND sort-key/val emission (lane 0)
template <int SCORE>
__global__ __launch_bounds__(256) void agg_pull(const float* __restrict__ H,
                                                const int* __restrict__ offs,
                                                const int* __restrict__ counts,
                                                const int* __restrict__ csr,
                                                const float* __restrict__ dinv,
                                                const float* __restrict__ bias,
                                                float* __restrict__ Y,
                                                const float* __restrict__ Wp,
                                                const float* __restrict__ bp,
                                                float* __restrict__ sc,
                                                unsigned* __restrict__ keys,
                                                int* __restrict__ vals) {
    int lane = threadIdx.x & 63;
    int node = blockIdx.x * 4 + (threadIdx.x >> 6);
    if (node >= NN) return;
    float dv = dinv[node];
    float acc = H[(size_t)node * 64 + lane];  // self-loop (pre-scaled)
    int off = offs[node], cnt = counts[node];
    int i = 0;
    for (; i + 7 < cnt; i += 8) {
        int p0 = csr[off + i];
        int p1 = csr[off + i + 1];
        int p2 = csr[off + i + 2];
        int p3 = csr[off + i + 3];
        int p4 = csr[off + i + 4];
        int p5 = csr[off + i + 5];
        int p6 = csr[off + i + 6];
        int p7 = csr[off + i + 7];
        float h0 = H[(size_t)p0 * 64 + lane];
        float h1 = H[(size_t)p1 * 64 + lane];
        float h2 = H[(size_t)p2 * 64 + lane];
        float h3 = H[(size_t)p3 * 64 + lane];
        float h4 = H[(size_t)p4 * 64 + lane];
        float h5 = H[(size_t)p5 * 64 + lane];
        float h6 = H[(size_t)p6 * 64 + lane];
        float h7 = H[(size_t)p7 * 64 + lane];
        acc += ((h0 + h1) + (h2 + h3)) + ((h4 + h5) + (h6 + h7));
    }
    for (; i < cnt; i++) {
        acc += H[(size_t)csr[off + i] * 64 + lane];
    }
    float o = acc * dv + bias[lane];
    Y[(size_t)node * 64 + lane] = o;
    if (SCORE) {
        float v = o * Wp[lane];
        for (int of = 32; of; of >>= 1) v += __shfl_down(v, of, 64);
        if (lane == 0) {
            float s = v + bp[0];
            sc[node] = s;
            unsigned u = __float_as_uint(s);
            u = (u & 0x80000000u) ? ~u : (u | 0x80000000u);
            keys[node] = u;
            vals[node] = node;
        }
    }
}

// ---------------- radix sort (4 passes x 8 bits, stable) ----------------
__global__ __launch_bounds__(256) void radix_hist(const unsigned* __restrict__ keys,
                                                  int* __restrict__ hist, int shift) {
    __shared__ int h[256];
    int t = threadIdx.x;
    h[t] = 0;
    __syncthreads();
    int base = blockIdx.x * 1024;
    for (int i = t; i < 1024; i += 256) {
        int idx = base + i;
        if (idx < NN) atomicAdd(&h[(keys[idx] >> shift) & 255], 1);
    }
    __syncthreads();
    hist[t * RBLK + blockIdx.x] = h[t];  // digit-major
}

__global__ __launch_bounds__(1024) void radix_scan(int* hist) {
    __shared__ int partial[1024];
    int t = threadIdx.x;
    int base = t * RSEG;
    int loc[RSEG];
    int s = 0;
#pragma unroll
    for (int i = 0; i < RSEG; i++) {
        int idx = base + i;
        int v = (idx < NENT) ? hist[idx] : 0;
        loc[i] = s;
        s += v;
    }
    partial[t] = s;
    __syncthreads();
    for (int o = 1; o < 1024; o <<= 1) {
        int add = (t >= o) ? partial[t - o] : 0;
        __syncthreads();
        partial[t] += add;
        __syncthreads();
    }
    int ex = partial[t] - s;
#pragma unroll
    for (int i = 0; i < RSEG; i++) {
        int idx = base + i;
        if (idx < NENT) hist[idx] = ex + loc[i];
    }
}

__global__ __launch_bounds__(256) void radix_scatter(const unsigned* __restrict__ keys_in,
                                                     const int* __restrict__ vals_in,
                                                     const int* __restrict__ hist,
                                                     unsigned* __restrict__ keys_out,
                                                     int* __restrict__ vals_out, int shift) {
    __shared__ int cursor[256];
    __shared__ int whist[4][256];
    __shared__ int wbase[4][256];
    int t = threadIdx.x, w = t >> 6, lane = t & 63;
    cursor[t] = hist[t * RBLK + blockIdx.x];
    __syncthreads();
    int base = blockIdx.x * 1024;
    for (int r = 0; r < 4; r++) {
        int idx = base + r * 256 + t;
        bool active = idx < NN;
        unsigned key = 0;
        int val = 0, d = -1;
        if (active) {
            key = keys_in[idx];
            val = vals_in[idx];
            d = (key >> shift) & 255;
        }
#pragma unroll
        for (int q = 0; q < 4; q++) whist[q][t] = 0;
        __syncthreads();
        // wave-level same-digit matching via 8 ballots
        unsigned long long m = __ballot(active);
#pragma unroll
        for (int b = 0; b < 8; b++) {
            unsigned long long bb = __ballot(active && ((d >> b) & 1));
            m &= ((d >> b) & 1) ? bb : ~bb;
        }
        unsigned long long below = ((unsigned long long)1 << lane) - 1;
        int rank_in_wave = __popcll(m & below);
        int cnt_in_wave = __popcll(m);
        if (active && rank_in_wave == 0) whist[w][d] = cnt_in_wave;
        __syncthreads();
        int c0 = whist[0][t], c1 = whist[1][t], c2 = whist[2][t], c3 = whist[3][t];
        wbase[0][t] = 0;
        wbase[1][t] = c0;
        wbase[2][t] = c0 + c1;
        wbase[3][t] = c0 + c1 + c2;
        __syncthreads();
        if (active) {
            int pos = cursor[d] + wbase[w][d] + rank_in_wave;
            keys_out[pos] = key;
            vals_out[pos] = val;
        }
        __syncthreads();
        cursor[t] += c0 + c1 + c2 + c3;
    }
}

// ---------------- conv1d (C=64, K=5, pad=2), 64 rows/block, 2 cols/thread ----------------
// GATHER: stage score[v]*X[v] for v=vals[row] (fuses build_sorted) + emit inverse perm
template <bool GATHER>
__global__ __launch_bounds__(256) void conv1d_k(const float* __restrict__ X,
                                                const int* __restrict__ vals,
                                                const float* __restrict__ sc,
                                                const float4* __restrict__ cw,
                                                const float* __restrict__ bias,
                                                float* __restrict__ Y, int relu,
                                                int* __restrict__ inv) {
    __shared__ float4 xs[68][16];
    int tid = threadIdx.x;
    int r0 = blockIdx.x * 64;
    for (int idx = tid; idx < 68 * 16; idx += 256) {
        int r = idx >> 4, k4 = idx & 15;
        int row = r0 + r - 2;
        float4 v = make_float4(0.f, 0.f, 0.f, 0.f);
        if (row >= 0 && row < NN) {
            if (GATHER) {
                int vs = vals[row];
                float s = sc[vs];
                v = *reinterpret_cast<const float4*>(X + (size_t)vs * 64 + 4 * k4);
                v.x *= s; v.y *= s; v.z *= s; v.w *= s;
                if (k4 == 0) inv[vs] = row;  // fused inverse perm (halo dups benign)
            } else {
                v = *reinterpret_cast<const float4*>(X + (size_t)row * 64 + 4 * k4);
            }
        }
        xs[r][k4] = v;
    }
    __syncthreads();
    int co2 = tid & 31, rg = tid >> 5;  // rg 0..7, 8 rows each
    int c0 = 2 * co2;
    float acc0[8], acc1[8];
#pragma unroll
    for (int i = 0; i < 8; i++) { acc0[i] = 0.f; acc1[i] = 0.f; }
    for (int j = 0; j < 16; j++) {
        float4 xv[12];
#pragma unroll
        for (int t2 = 0; t2 < 12; t2++) xv[t2] = xs[rg * 8 + t2][j];
#pragma unroll
        for (int k = 0; k < 5; k++) {
            float4 wa = cw[(k * 16 + j) * 64 + c0];
            float4 wb = cw[(k * 16 + j) * 64 + c0 + 1];
#pragma unroll
            for (int i = 0; i < 8; i++) {
                float4 x4 = xv[i + k];
                acc0[i] += x4.x * wa.x + x4.y * wa.y + x4.z * wa.z + x4.w * wa.w;
                acc1[i] += x4.x * wb.x + x4.y * wb.y + x4.z * wb.z + x4.w * wb.w;
            }
        }
    }
    float b0v = bias[c0], b1v = bias[c0 + 1];
#pragma unroll
    for (int i = 0; i < 8; i++) {
        int row = r0 + rg * 8 + i;
        if (row < NN) {
            float o0 = acc0[i] + b0v, o1 = acc1[i] + b1v;
            if (relu) { o0 = fmaxf(o0, 0.f); o1 = fmaxf(o1, 0.f); }
            *reinterpret_cast<float2*>(Y + (size_t)row * 64 + c0) = make_float2(o0, o1);
        }
    }
}

// ---------------- final: out[n] = [C[n], H2[inv[n]]] @ lin_w + lb, 64 rows/block ----------------
__global__ __launch_bounds__(256) void final_k(const float* __restrict__ C,
                                               const float* __restrict__ H2,
                                               const int* __restrict__ inv,
                                               const float4* __restrict__ linsw,
                                               const float* __restrict__ lb,
                                               float* __restrict__ Yout) {
    __shared__ float4 xs[64][32];
    int tid = threadIdx.x;
    int r0 = blockIdx.x * 64;
    for (int idx = tid; idx < 64 * 32; idx += 256) {
        int r = idx >> 5, k4 = idx & 31;
        int row = r0 + r;
        float4 v = make_float4(0.f, 0.f, 0.f, 0.f);
        if (row < NN) {
            if (k4 < 16) v = *reinterpret_cast<const float4*>(C + (size_t)row * 64 + 4 * k4);
            else v = *reinterpret_cast<const float4*>(H2 + (size_t)inv[row] * 64 + 4 * (k4 - 16));
        }
        xs[r][k4] = v;
    }
    __syncthreads();
    int co2 = tid & 31, rg = tid >> 5;
    int c0 = 2 * co2;
    float acc0[8], acc1[8];
#pragma unroll
    for (int i = 0; i < 8; i++) { acc0[i] = 0.f; acc1[i] = 0.f; }
    for (int k4 = 0; k4 < 32; k4++) {
        float4 wa = linsw[k4 * 64 + c0];
        float4 wb = linsw[k4 * 64 + c0 + 1];
#pragma unroll
        for (int i = 0; i < 8; i++) {
            float4 xv = xs[rg * 8 + i][k4];
            acc0[i] += xv.x * wa.x + xv.y * wa.y + xv.z * wa.z + xv.w * wa.w;
            acc1[i] += xv.x * wb.x + xv.y * wb.y + xv.z * wb.z + xv.w * wb.w;
        }
    }
    float b0v = lb[c0], b1v = lb[c0 + 1];
#pragma unroll
    for (int i = 0; i < 8; i++) {
        int row = r0 + rg * 8 + i;
        if (row < NN)
            *reinterpret_cast<float2*>(Yout + (size_t)row * 64 + c0) =
                make_float2(acc0[i] + b0v, acc1[i] + b1v);
    }
}

extern "C" void kernel_launch(void* const* d_in, const int* in_sizes, int n_in,
                              void* d_out, int out_size, void* d_ws, size_t ws_size,
                              hipStream_t stream) {
    const float* x   = (const float*)d_in[0];
    const int*   ei  = (const int*)d_in[1];
    const float* W0  = (const float*)d_in[2];
    const float* b0  = (const float*)d_in[3];
    const float* W1  = (const float*)d_in[4];
    const float* b1  = (const float*)d_in[5];
    const float* W2  = (const float*)d_in[6];
    const float* b2  = (const float*)d_in[7];
    const float* Wp  = (const float*)d_in[8];
    const float* bp  = (const float*)d_in[9];
    const float* c1w = (const float*)d_in[10];
    const float* c1b = (const float*)d_in[11];
    const float* c2w = (const float*)d_in[12];
    const float* c2b = (const float*)d_in[13];
    const float* lw  = (const float*)d_in[14];
    const float* lb  = (const float*)d_in[15];
    const int* src = ei;
    const int* dst = ei + NE;

    // workspace layout
    const int NNP = 100352;  // NN rounded up (alignment)
    float* A     = (float*)d_ws;                 // [NN*64]
    float* B     = A + (size_t)NN * 64;          // [NN*64]
    float* dinv  = B + (size_t)NN * 64;          // [NN]
    float* score = dinv + NNP;                   // [NN]
    unsigned* keys0 = (unsigned*)(score + NNP);  // [NNP]
    int* vals0   = (int*)(keys0 + NNP);          // [NNP]
    unsigned* keys1 = (unsigned*)(vals0 + NNP);  // [NNP]
    int* vals1   = (int*)(keys1 + NNP);          // [NNP]
    int* rhist   = vals1 + NNP;                  // [NENT]
    int* inv     = rhist + NENT;                 // [NN]
    int* counts  = inv + NNP;                    // [NN]
    int* offs    = counts + NNP;                 // [NN]
    int* cursor  = offs + NNP;                   // [NN]
    int* bsums   = cursor + NNP;                 // [128]
    int* csr     = bsums + 128;                  // [NE]
    float4* w0sw  = (float4*)(csr + NE);         // 2048
    float4* w1sw  = w0sw + 2048;                 // 1024
    float4* w2sw  = w1sw + 1024;                 // 1024
    float4* linsw = w2sw + 1024;                 // 2048
    float4* c1sw  = linsw + 2048;                // 5120
    float4* c2sw  = c1sw + 5120;                 // 5120
    float* Cb = (float*)d_out;  // h1 lives in d_out; final_k overwrites block-local rows

    const int GR64 = (NN + 63) / 64;       // 1563
    const int GN4 = (NN + 3) / 4;          // 25000 (agg_pull: 4 waves/block)
    const int GE = (NE + 255) / 256;       // 6250

    // CSR build (reused by all 3 layers) + dinv
    zero_counts<<<(NN + 255) / 256, 256, 0, stream>>>(counts);
    count_dst<<<GE, 256, 0, stream>>>(dst, counts);
    scan_p1<<<NB_SCAN, 256, 0, stream>>>(counts, bsums);
    scan_p2<<<1, 128, 0, stream>>>(bsums);
    scan_p3<<<NB_SCAN, 256, 0, stream>>>(counts, bsums, offs, cursor, dinv);
    csr_scatter<<<GE, 256, 0, stream>>>(src, dst, cursor, csr);

    // weight swizzles (single kernel)
    swizzle_all<<<64, 256, 0, stream>>>(W0, W1, W2, lw, c1w, c2w,
                                        w0sw, w1sw, w2sw, linsw, c1sw, c2sw);

    // layer 0: A = (x@W0)*dinv ; B = dv*(selfA + sum A[src]) + b0
    gemm64r<128, false><<<GR64, 256, 0, stream>>>(x, w0sw, dinv, A, NN);
    agg_pull<0><<<GN4, 256, 0, stream>>>(A, offs, counts, csr, dinv, b0, B,
                                         nullptr, nullptr, nullptr, nullptr, nullptr);
    // layer 1
    gemm64r<64, true><<<GR64, 256, 0, stream>>>(B, w1sw, dinv, A, NN);
    agg_pull<0><<<GN4, 256, 0, stream>>>(A, offs, counts, csr, dinv, b1, B,
                                         nullptr, nullptr, nullptr, nullptr, nullptr);
    // layer 2: Cb = h1 ; score + sort keys fused
    gemm64r<64, true><<<GR64, 256, 0, stream>>>(B, w2sw, dinv, A, NN);
    agg_pull<1><<<GN4, 256, 0, stream>>>(A, offs, counts, csr, dinv, b2, Cb,
                                         Wp, bp, score, keys0, vals0);

    // radix sort: 4 stable passes of 8 bits; ends back in keys0/vals0
    radix_hist<<<RBLK, 256, 0, stream>>>(keys0, rhist, 0);
    radix_scan<<<1, 1024, 0, stream>>>(rhist);
    radix_scatter<<<RBLK, 256, 0, stream>>>(keys0, vals0, rhist, keys1, vals1, 0);
    radix_hist<<<RBLK, 256, 0, stream>>>(keys1, rhist, 8);
    radix_scan<<<1, 1024, 0, stream>>>(rhist);
    radix_scatter<<<RBLK, 256, 0, stream>>>(keys1, vals1, rhist, keys0, vals0, 8);
    radix_hist<<<RBLK, 256, 0, stream>>>(keys0, rhist, 16);
    radix_scan<<<1, 1024, 0, stream>>>(rhist);
    radix_scatter<<<RBLK, 256, 0, stream>>>(keys0, vals0, rhist, keys1, vals1, 16);
    radix_hist<<<RBLK, 256, 0, stream>>>(keys1, rhist, 24);
    radix_scan<<<1, 1024, 0, stream>>>(rhist);
    radix_scatter<<<RBLK, 256, 0, stream>>>(keys1, vals1, rhist, keys0, vals0, 24);

    // conv1 (gather-fused: stages score[v]*h1[v], emits inv) -> B ; conv2 -> A
    conv1d_k<true><<<GR64, 256, 0, stream>>>(Cb, vals0, score, c1sw, c1b, B, 1, inv);
    conv1d_k<false><<<GR64, 256, 0, stream>>>(B, nullptr, nullptr, c2sw, c2b, A, 0, nullptr);

    // final linear
    final_k<<<GR64, 256, 0, stream>>>(Cb, A, inv, linsw, lb, (float*)d_out);
}

// Round 8
// 783.854 us; speedup vs baseline: 1.2410x; 1.1788x over previous
//
#include <hip/hip_runtime.h>

#define NN 100000
#define NE 1600000
#define NBUK 391       // ceil(NN/256) buckets by dst>>8
#define RBLK 98        // radix: ceil(NN/1024)
#define NENT (256 * RBLK)
#define RSEG 25        // ceil(NENT/1024)
#define BS_CHUNK 8192  // edges per bucket_scatter block
#define NBS 196        // ceil(NE/BS_CHUNK)

// ---------------- bucketed CSR build ----------------
__global__ void zero_bhist(int* bhist) {
    int i = blockIdx.x * blockDim.x + threadIdx.x;
    if (i < NBUK) bhist[i] = 0;
}

__global__ __launch_bounds__(256) void bucket_hist(const int* __restrict__ dst, int* __restrict__ bhist) {
    __shared__ int h[NBUK];
    int t = threadIdx.x;
    for (int b = t; b < NBUK; b += 256) h[b] = 0;
    __syncthreads();
    int base = blockIdx.x * BS_CHUNK;
    for (int i = t; i < BS_CHUNK; i += 256) {
        int e = base + i;
        if (e < NE) atomicAdd(&h[dst[e] >> 8], 1);
    }
    __syncthreads();
    for (int b = t; b < NBUK; b += 256)
        if (h[b]) atomicAdd(&bhist[b], h[b]);
}

__global__ __launch_bounds__(512) void bucket_scan(const int* __restrict__ bhist,
                                                   int* __restrict__ bbase, int* __restrict__ bcur) {
    __shared__ int tmp[512];
    int t = threadIdx.x;
    int v = (t < NBUK) ? bhist[t] : 0;
    tmp[t] = v; __syncthreads();
    for (int o = 1; o < 512; o <<= 1) {
        int add = (t >= o) ? tmp[t - o] : 0;
        __syncthreads();
        tmp[t] += add;
        __syncthreads();
    }
    int ex = tmp[t] - v;
    if (t < NBUK) { bbase[t] = ex; bcur[t] = ex; }
    if (t == NBUK - 1) bbase[NBUK] = ex + v;  // == NE
}

// per-block: LDS bucket counts -> one global reservation per bucket -> local scatter
__global__ __launch_bounds__(256) void bucket_scatter(const int* __restrict__ src,
                                                      const int* __restrict__ dst,
                                                      int* __restrict__ bcur,
                                                      unsigned* __restrict__ stage) {
    __shared__ int h[NBUK];
    int t = threadIdx.x;
    for (int b = t; b < NBUK; b += 256) h[b] = 0;
    __syncthreads();
    int base = blockIdx.x * BS_CHUNK;
    for (int i = t; i < BS_CHUNK; i += 256) {
        int e = base + i;
        if (e < NE) atomicAdd(&h[dst[e] >> 8], 1);
    }
    __syncthreads();
    for (int b = t; b < NBUK; b += 256) {
        int c = h[b];
        h[b] = c ? atomicAdd(&bcur[b], c) : 0;  // h[b] becomes running global cursor
    }
    __syncthreads();
    for (int i = t; i < BS_CHUNK; i += 256) {
        int e = base + i;
        if (e < NE) {
            int d = dst[e];
            int p = atomicAdd(&h[d >> 8], 1);
            stage[p] = ((unsigned)src[e] << 8) | (unsigned)(d & 255);
        }
    }
}

// one block per bucket: build per-node counts/offs/dinv + place csr entries (region block-exclusive)
__global__ __launch_bounds__(256) void csr_place(const unsigned* __restrict__ stage,
                                                 const int* __restrict__ bbase,
                                                 int* __restrict__ csr,
                                                 int* __restrict__ counts,
                                                 int* __restrict__ offs,
                                                 float* __restrict__ dinv) {
    __shared__ int cnt[256];
    __shared__ int cursor[256];
    int b = blockIdx.x, t = threadIdx.x;
    int start = bbase[b], end = bbase[b + 1];
    cnt[t] = 0;
    __syncthreads();
    for (int idx = start + t; idx < end; idx += 256)
        atomicAdd(&cnt[stage[idx] & 255u], 1);
    __syncthreads();
    int c = cnt[t];
    // exclusive scan of cnt[256]
    __shared__ int tmp[256];
    tmp[t] = c; __syncthreads();
    for (int o = 1; o < 256; o <<= 1) {
        int add = (t >= o) ? tmp[t - o] : 0;
        __syncthreads();
        tmp[t] += add;
        __syncthreads();
    }
    int pos = start + tmp[t] - c;
    cursor[t] = pos;
    int node = b * 256 + t;
    if (node < NN) {
        offs[node] = pos;
        counts[node] = c;
        dinv[node] = rsqrtf((float)(c + 1));  // +1 self-loop
    }
    __syncthreads();
    for (int idx = start + t; idx < end; idx += 256) {
        unsigned u = stage[idx];
        int p = atomicAdd(&cursor[u & 255u], 1);
        csr[p] = (int)(u >> 8);
    }
}

// ---------------- weight swizzles (single kernel) ----------------
__device__ inline void swz_w(const float* __restrict__ W, float4* __restrict__ o, int idx) {
    int k4 = idx >> 6, co = idx & 63;
    o[idx] = make_float4(W[(4 * k4 + 0) * 64 + co], W[(4 * k4 + 1) * 64 + co],
                         W[(4 * k4 + 2) * 64 + co], W[(4 * k4 + 3) * 64 + co]);
}

__device__ inline void swz_c(const float* __restrict__ w, float4* __restrict__ o, int idx) {
    int co = idx & 63, j = (idx >> 6) & 15, k = idx >> 10;
    int b = co * 320 + k;  // w[co][ci][k] = w[co*320 + ci*5 + k], ci=4j+t
    o[idx] = make_float4(w[b + (4 * j + 0) * 5], w[b + (4 * j + 1) * 5],
                         w[b + (4 * j + 2) * 5], w[b + (4 * j + 3) * 5]);
}

__global__ void swizzle_all(const float* W0, const float* W1, const float* W2,
                            const float* lw, const float* c1w, const float* c2w,
                            float4* w0sw, float4* w1sw, float4* w2sw,
                            float4* linsw, float4* c1sw, float4* c2sw) {
    int idx = blockIdx.x * blockDim.x + threadIdx.x;
    if (idx < 2048)        swz_w(W0, w0sw, idx);
    else if (idx < 3072)   swz_w(W1, w1sw, idx - 2048);
    else if (idx < 4096)   swz_w(W2, w2sw, idx - 3072);
    else if (idx < 6144)   swz_w(lw, linsw, idx - 4096);
    else if (idx < 11264)  swz_c(c1w, c1sw, idx - 6144);
    else if (idx < 16384)  swz_c(c2w, c2sw, idx - 11264);
}

// ---------------- GEMM: Y[N][64] = (relu?)X[N][K] @ W[K][64] * dinv[row] ----------------
template <int K, bool RELU>
__global__ __launch_bounds__(256) void gemm64r(const float* __restrict__ X,
                                               const float4* __restrict__ Wsw,
                                               const float* __restrict__ dinv,
                                               float* __restrict__ Y, int n) {
    constexpr int KV = K / 4;
    constexpr int SH = (KV == 32) ? 5 : 4;
    __shared__ float4 xs[64][KV];
    int tid = threadIdx.x;
    int r0 = blockIdx.x * 64;
    for (int idx = tid; idx < 64 * KV; idx += 256) {
        int r = idx >> SH, k4 = idx & (KV - 1);
        int row = r0 + r;
        float4 v = make_float4(0.f, 0.f, 0.f, 0.f);
        if (row < n) v = *reinterpret_cast<const float4*>(X + (size_t)row * K + 4 * k4);
        if (RELU) {
            v.x = fmaxf(v.x, 0.f); v.y = fmaxf(v.y, 0.f);
            v.z = fmaxf(v.z, 0.f); v.w = fmaxf(v.w, 0.f);
        }
        xs[r][k4] = v;
    }
    __syncthreads();
    int co2 = tid & 31, rg = tid >> 5;  // rg 0..7, 8 rows each
    int c0 = 2 * co2;
    float acc0[8], acc1[8];
#pragma unroll
    for (int i = 0; i < 8; i++) { acc0[i] = 0.f; acc1[i] = 0.f; }
    for (int k4 = 0; k4 < KV; k4++) {
        float4 wa = Wsw[k4 * 64 + c0];
        float4 wb = Wsw[k4 * 64 + c0 + 1];
#pragma unroll
        for (int i = 0; i < 8; i++) {
            float4 xv = xs[rg * 8 + i][k4];
            acc0[i] += xv.x * wa.x + xv.y * wa.y + xv.z * wa.z + xv.w * wa.w;
            acc1[i] += xv.x * wb.x + xv.y * wb.y + xv.z * wb.z + xv.w * wb.w;
        }
    }
#pragma unroll
    for (int i = 0; i < 8; i++) {
        int row = r0 + rg * 8 + i;
        if (row < n) {
            float dv = dinv[row];
            *reinterpret_cast<float2*>(Y + (size_t)row * 64 + c0) =
                make_float2(acc0[i] * dv, acc1[i] * dv);
        }
    }
}

// ---------------- pull aggregation: one wave per node ----------------
// H is pre-scaled by dinv: out[d] = dv*(H'[d] + sum H'[src]) + bias
// SCORE: fuse score projection AND sort-key/val emission (lane 0)
template <int SCORE>
__global__ __launch_bounds__(256) void agg_pull(const float* __restrict__ H,
                                                const int* __restrict__ offs,
                                                const int* __restrict__ counts,
                                                const int* __restrict__ csr,
                                                const float* __restrict__ dinv,
                                                const float* __restrict__ bias,
                                                float* __restrict__ Y,
                                                const float* __restrict__ Wp,
                                                const float* __restrict__ bp,
                                                float* __restrict__ sc,
                                                unsigned* __restrict__ keys,
                                                int* __restrict__ vals) {
    int lane = threadIdx.x & 63;
    int node = blockIdx.x * 4 + (threadIdx.x >> 6);
    if (node >= NN) return;
    float dv = dinv[node];
    float acc = H[(size_t)node * 64 + lane];  // self-loop (pre-scaled)
    int off = offs[node], cnt = counts[node];
    int i = 0;
    for (; i + 7 < cnt; i += 8) {
        int p0 = csr[off + i];
        int p1 = csr[off + i + 1];
        int p2 = csr[off + i + 2];
        int p3 = csr[off + i + 3];
        int p4 = csr[off + i + 4];
        int p5 = csr[off + i + 5];
        int p6 = csr[off + i + 6];
        int p7 = csr[off + i + 7];
        float h0 = H[(size_t)p0 * 64 + lane];
        float h1 = H[(size_t)p1 * 64 + lane];
        float h2 = H[(size_t)p2 * 64 + lane];
        float h3 = H[(size_t)p3 * 64 + lane];
        float h4 = H[(size_t)p4 * 64 + lane];
        float h5 = H[(size_t)p5 * 64 + lane];
        float h6 = H[(size_t)p6 * 64 + lane];
        float h7 = H[(size_t)p7 * 64 + lane];
        acc += ((h0 + h1) + (h2 + h3)) + ((h4 + h5) + (h6 + h7));
    }
    for (; i < cnt; i++) {
        acc += H[(size_t)csr[off + i] * 64 + lane];
    }
    float o = acc * dv + bias[lane];
    Y[(size_t)node * 64 + lane] = o;
    if (SCORE) {
        float v = o * Wp[lane];
        for (int of = 32; of; of >>= 1) v += __shfl_down(v, of, 64);
        if (lane == 0) {
            float s = v + bp[0];
            sc[node] = s;
            unsigned u = __float_as_uint(s);
            u = (u & 0x80000000u) ? ~u : (u | 0x80000000u);
            keys[node] = u;
            vals[node] = node;
        }
    }
}

// ---------------- radix sort (4 passes x 8 bits, stable) ----------------
__global__ __launch_bounds__(256) void radix_hist(const unsigned* __restrict__ keys,
                                                  int* __restrict__ hist, int shift) {
    __shared__ int h[256];
    int t = threadIdx.x;
    h[t] = 0;
    __syncthreads();
    int base = blockIdx.x * 1024;
    for (int i = t; i < 1024; i += 256) {
        int idx = base + i;
        if (idx < NN) atomicAdd(&h[(keys[idx] >> shift) & 255], 1);
    }
    __syncthreads();
    hist[t * RBLK + blockIdx.x] = h[t];  // digit-major
}

__global__ __launch_bounds__(1024) void radix_scan(int* hist) {
    __shared__ int partial[1024];
    int t = threadIdx.x;
    int base = t * RSEG;
    int loc[RSEG];
    int s = 0;
#pragma unroll
    for (int i = 0; i < RSEG; i++) {
        int idx = base + i;
        int v = (idx < NENT) ? hist[idx] : 0;
        loc[i] = s;
        s += v;
    }
    partial[t] = s;
    __syncthreads();
    for (int o = 1; o < 1024; o <<= 1) {
        int add = (t >= o) ? partial[t - o] : 0;
        __syncthreads();
        partial[t] += add;
        __syncthreads();
    }
    int ex = partial[t] - s;
#pragma unroll
    for (int i = 0; i < RSEG; i++) {
        int idx = base + i;
        if (idx < NENT) hist[idx] = ex + loc[i];
    }
}

__global__ __launch_bounds__(256) void radix_scatter(const unsigned* __restrict__ keys_in,
                                                     const int* __restrict__ vals_in,
                                                     const int* __restrict__ hist,
                                                     unsigned* __restrict__ keys_out,
                                                     int* __restrict__ vals_out, int shift) {
    __shared__ int cursor[256];
    __shared__ int whist[4][256];
    __shared__ int wbase[4][256];
    int t = threadIdx.x, w = t >> 6, lane = t & 63;
    cursor[t] = hist[t * RBLK + blockIdx.x];
    __syncthreads();
    int base = blockIdx.x * 1024;
    for (int r = 0; r < 4; r++) {
        int idx = base + r * 256 + t;
        bool active = idx < NN;
        unsigned key = 0;
        int val = 0, d = -1;
        if (active) {
            key = keys_in[idx];
            val = vals_in[idx];
            d = (key >> shift) & 255;
        }
#pragma unroll
        for (int q = 0; q < 4; q++) whist[q][t] = 0;
        __syncthreads();
        // wave-level same-digit matching via 8 ballots
        unsigned long long m = __ballot(active);
#pragma unroll
        for (int b = 0; b < 8; b++) {
            unsigned long long bb = __ballot(active && ((d >> b) & 1));
            m &= ((d >> b) & 1) ? bb : ~bb;
        }
        unsigned long long below = ((unsigned long long)1 << lane) - 1;
        int rank_in_wave = __popcll(m & below);
        int cnt_in_wave = __popcll(m);
        if (active && rank_in_wave == 0) whist[w][d] = cnt_in_wave;
        __syncthreads();
        int c0 = whist[0][t], c1 = whist[1][t], c2 = whist[2][t], c3 = whist[3][t];
        wbase[0][t] = 0;
        wbase[1][t] = c0;
        wbase[2][t] = c0 + c1;
        wbase[3][t] = c0 + c1 + c2;
        __syncthreads();
        if (active) {
            int pos = cursor[d] + wbase[w][d] + rank_in_wave;
            keys_out[pos] = key;
            vals_out[pos] = val;
        }
        __syncthreads();
        cursor[t] += c0 + c1 + c2 + c3;
    }
}

// ---------------- conv1d (C=64, K=5, pad=2), 64 rows/block, 2 cols/thread ----------------
// GATHER: stage score[v]*X[v] for v=vals[row] (fuses build_sorted) + emit inverse perm
template <bool GATHER>
__global__ __launch_bounds__(256) void conv1d_k(const float* __restrict__ X,
                                                const int* __restrict__ vals,
                                                const float* __restrict__ sc,
                                                const float4* __restrict__ cw,
                                                const float* __restrict__ bias,
                                                float* __restrict__ Y, int relu,
                                                int* __restrict__ inv) {
    __shared__ float4 xs[68][16];
    int tid = threadIdx.x;
    int r0 = blockIdx.x * 64;
    for (int idx = tid; idx < 68 * 16; idx += 256) {
        int r = idx >> 4, k4 = idx & 15;
        int row = r0 + r - 2;
        float4 v = make_float4(0.f, 0.f, 0.f, 0.f);
        if (row >= 0 && row < NN) {
            if (GATHER) {
                int vs = vals[row];
                float s = sc[vs];
                v = *reinterpret_cast<const float4*>(X + (size_t)vs * 64 + 4 * k4);
                v.x *= s; v.y *= s; v.z *= s; v.w *= s;
                if (k4 == 0) inv[vs] = row;  // fused inverse perm (halo dups benign)
            } else {
                v = *reinterpret_cast<const float4*>(X + (size_t)row * 64 + 4 * k4);
            }
        }
        xs[r][k4] = v;
    }
    __syncthreads();
    int co2 = tid & 31, rg = tid >> 5;  // rg 0..7, 8 rows each
    int c0 = 2 * co2;
    float acc0[8], acc1[8];
#pragma unroll
    for (int i = 0; i < 8; i++) { acc0[i] = 0.f; acc1[i] = 0.f; }
    for (int j = 0; j < 16; j++) {
        float4 xv[12];
#pragma unroll
        for (int t2 = 0; t2 < 12; t2++) xv[t2] = xs[rg * 8 + t2][j];
#pragma unroll
        for (int k = 0; k < 5; k++) {
            float4 wa = cw[(k * 16 + j) * 64 + c0];
            float4 wb = cw[(k * 16 + j) * 64 + c0 + 1];
#pragma unroll
            for (int i = 0; i < 8; i++) {
                float4 x4 = xv[i + k];
                acc0[i] += x4.x * wa.x + x4.y * wa.y + x4.z * wa.z + x4.w * wa.w;
                acc1[i] += x4.x * wb.x + x4.y * wb.y + x4.z * wb.z + x4.w * wb.w;
            }
        }
    }
    float b0v = bias[c0], b1v = bias[c0 + 1];
#pragma unroll
    for (int i = 0; i < 8; i++) {
        int row = r0 + rg * 8 + i;
        if (row < NN) {
            float o0 = acc0[i] + b0v, o1 = acc1[i] + b1v;
            if (relu) { o0 = fmaxf(o0, 0.f); o1 = fmaxf(o1, 0.f); }
            *reinterpret_cast<float2*>(Y + (size_t)row * 64 + c0) = make_float2(o0, o1);
        }
    }
}

// ---------------- final: out[n] = [C[n], H2[inv[n]]] @ lin_w + lb, 64 rows/block ----------------
__global__ __launch_bounds__(256) void final_k(const float* __restrict__ C,
                                               const float* __restrict__ H2,
                                               const int* __restrict__ inv,
                                               const float4* __restrict__ linsw,
                                               const float* __restrict__ lb,
                                               float* __restrict__ Yout) {
    __shared__ float4 xs[64][32];
    int tid = threadIdx.x;
    int r0 = blockIdx.x * 64;
    for (int idx = tid; idx < 64 * 32; idx += 256) {
        int r = idx >> 5, k4 = idx & 31;
        int row = r0 + r;
        float4 v = make_float4(0.f, 0.f, 0.f, 0.f);
        if (row < NN) {
            if (k4 < 16) v = *reinterpret_cast<const float4*>(C + (size_t)row * 64 + 4 * k4);
            else v = *reinterpret_cast<const float4*>(H2 + (size_t)inv[row] * 64 + 4 * (k4 - 16));
        }
        xs[r][k4] = v;
    }
    __syncthreads();
    int co2 = tid & 31, rg = tid >> 5;
    int c0 = 2 * co2;
    float acc0[8], acc1[8];
#pragma unroll
    for (int i = 0; i < 8; i++) { acc0[i] = 0.f; acc1[i] = 0.f; }
    for (int k4 = 0; k4 < 32; k4++) {
        float4 wa = linsw[k4 * 64 + c0];
        float4 wb = linsw[k4 * 64 + c0 + 1];
#pragma unroll
        for (int i = 0; i < 8; i++) {
            float4 xv = xs[rg * 8 + i][k4];
            acc0[i] += xv.x * wa.x + xv.y * wa.y + xv.z * wa.z + xv.w * wa.w;
            acc1[i] += xv.x * wb.x + xv.y * wb.y + xv.z * wb.z + xv.w * wb.w;
        }
    }
    float b0v = lb[c0], b1v = lb[c0 + 1];
#pragma unroll
    for (int i = 0; i < 8; i++) {
        int row = r0 + rg * 8 + i;
        if (row < NN)
            *reinterpret_cast<float2*>(Yout + (size_t)row * 64 + c0) =
                make_float2(acc0[i] + b0v, acc1[i] + b1v);
    }
}

extern "C" void kernel_launch(void* const* d_in, const int* in_sizes, int n_in,
                              void* d_out, int out_size, void* d_ws, size_t ws_size,
                              hipStream_t stream) {
    const float* x   = (const float*)d_in[0];
    const int*   ei  = (const int*)d_in[1];
    const float* W0  = (const float*)d_in[2];
    const float* b0  = (const float*)d_in[3];
    const float* W1  = (const float*)d_in[4];
    const float* b1  = (const float*)d_in[5];
    const float* W2  = (const float*)d_in[6];
    const float* b2  = (const float*)d_in[7];
    const float* Wp  = (const float*)d_in[8];
    const float* bp  = (const float*)d_in[9];
    const float* c1w = (const float*)d_in[10];
    const float* c1b = (const float*)d_in[11];
    const float* c2w = (const float*)d_in[12];
    const float* c2b = (const float*)d_in[13];
    const float* lw  = (const float*)d_in[14];
    const float* lb  = (const float*)d_in[15];
    const int* src = ei;
    const int* dst = ei + NE;

    // workspace layout
    const int NNP = 100352;  // NN rounded up (alignment)
    float* A     = (float*)d_ws;                 // [NN*64]
    float* B     = A + (size_t)NN * 64;          // [NN*64]
    float* dinv  = B + (size_t)NN * 64;          // [NNP]
    float* score = dinv + NNP;                   // [NNP]
    unsigned* keys0 = (unsigned*)(score + NNP);  // [NNP]
    int* vals0   = (int*)(keys0 + NNP);          // [NNP]
    unsigned* keys1 = (unsigned*)(vals0 + NNP);  // [NNP]
    int* vals1   = (int*)(keys1 + NNP);          // [NNP]
    int* rhist   = vals1 + NNP;                  // [NENT]
    int* inv     = rhist + NENT;                 // [NNP]
    int* counts  = inv + NNP;                    // [NNP]
    int* offs    = counts + NNP;                 // [NNP]
    int* bhist   = offs + NNP;                   // [512]
    int* bbase   = bhist + 512;                  // [512] (uses NBUK+1)
    int* bcur    = bbase + 512;                  // [512]
    unsigned* stage = (unsigned*)(bcur + 512);   // [NE]
    int* csr     = (int*)(stage + NE);           // [NE]
    float4* w0sw  = (float4*)(csr + NE);         // 2048
    float4* w1sw  = w0sw + 2048;                 // 1024
    float4* w2sw  = w1sw + 1024;                 // 1024
    float4* linsw = w2sw + 1024;                 // 2048
    float4* c1sw  = linsw + 2048;                // 5120
    float4* c2sw  = c1sw + 5120;                 // 5120
    float* Cb = (float*)d_out;  // h1 lives in d_out; final_k overwrites block-local rows

    const int GR64 = (NN + 63) / 64;       // 1563
    const int GN4 = (NN + 3) / 4;          // 25000 (agg_pull: 4 waves/block)

    // bucketed CSR build (replaces count/scan/scatter): also emits counts/offs/dinv
    zero_bhist<<<2, 256, 0, stream>>>(bhist);
    bucket_hist<<<NBS, 256, 0, stream>>>(dst, bhist);
    bucket_scan<<<1, 512, 0, stream>>>(bhist, bbase, bcur);
    bucket_scatter<<<NBS, 256, 0, stream>>>(src, dst, bcur, stage);
    csr_place<<<NBUK, 256, 0, stream>>>(stage, bbase, csr, counts, offs, dinv);

    // weight swizzles (single kernel)
    swizzle_all<<<64, 256, 0, stream>>>(W0, W1, W2, lw, c1w, c2w,
                                        w0sw, w1sw, w2sw, linsw, c1sw, c2sw);

    // layer 0: A = (x@W0)*dinv ; B = dv*(selfA + sum A[src]) + b0
    gemm64r<128, false><<<GR64, 256, 0, stream>>>(x, w0sw, dinv, A, NN);
    agg_pull<0><<<GN4, 256, 0, stream>>>(A, offs, counts, csr, dinv, b0, B,
                                         nullptr, nullptr, nullptr, nullptr, nullptr);
    // layer 1
    gemm64r<64, true><<<GR64, 256, 0, stream>>>(B, w1sw, dinv, A, NN);
    agg_pull<0><<<GN4, 256, 0, stream>>>(A, offs, counts, csr, dinv, b1, B,
                                         nullptr, nullptr, nullptr, nullptr, nullptr);
    // layer 2: Cb = h1 ; score + sort keys fused
    gemm64r<64, true><<<GR64, 256, 0, stream>>>(B, w2sw, dinv, A, NN);
    agg_pull<1><<<GN4, 256, 0, stream>>>(A, offs, counts, csr, dinv, b2, Cb,
                                         Wp, bp, score, keys0, vals0);

    // radix sort: 4 stable passes of 8 bits; ends back in keys0/vals0
    radix_hist<<<RBLK, 256, 0, stream>>>(keys0, rhist, 0);
    radix_scan<<<1, 1024, 0, stream>>>(rhist);
    radix_scatter<<<RBLK, 256, 0, stream>>>(keys0, vals0, rhist, keys1, vals1, 0);
    radix_hist<<<RBLK, 256, 0, stream>>>(keys1, rhist, 8);
    radix_scan<<<1, 1024, 0, stream>>>(rhist);
    radix_scatter<<<RBLK, 256, 0, stream>>>(keys1, vals1, rhist, keys0, vals0, 8);
    radix_hist<<<RBLK, 256, 0, stream>>>(keys0, rhist, 16);
    radix_scan<<<1, 1024, 0, stream>>>(rhist);
    radix_scatter<<<RBLK, 256, 0, stream>>>(keys0, vals0, rhist, keys1, vals1, 16);
    radix_hist<<<RBLK, 256, 0, stream>>>(keys1, rhist, 24);
    radix_scan<<<1, 1024, 0, stream>>>(rhist);
    radix_scatter<<<RBLK, 256, 0, stream>>>(keys1, vals1, rhist, keys0, vals0, 24);

    // conv1 (gather-fused: stages score[v]*h1[v], emits inv) -> B ; conv2 -> A
    conv1d_k<true><<<GR64, 256, 0, stream>>>(Cb, vals0, score, c1sw, c1b, B, 1, inv);
    conv1d_k<false><<<GR64, 256, 0, stream>>>(B, nullptr, nullptr, c2sw, c2b, A, 0, nullptr);

    // final linear
    final_k<<<GR64, 256, 0, stream>>>(Cb, A, inv, linsw, lb, (float*)d_out);
}